// Round 4
// baseline (6767.242 us; speedup 1.0000x reference)
//
#include <hip/hip_runtime.h>
#include <math.h>

#define NTHR 1024   // threads per block (2 threads per point)
#define DD   128    // feature dim
#define HD   64     // dims per thread

typedef unsigned long long ull;

// packed argmax key: (ordered f32)<<32 | ~idx  -> max() gives argmax with
// smallest-index tie-break, matching jnp.argmax first-occurrence.
__device__ __forceinline__ ull pkkey(float f, unsigned idx) {
  unsigned u = __float_as_uint(f);
  u = (u & 0x80000000u) ? ~u : (u | 0x80000000u);
  return ((ull)u << 32) | (ull)(~idx);
}

__device__ __forceinline__ ull wredmax(ull v) {
#pragma unroll
  for (int m = 32; m; m >>= 1) {
    ull o = __shfl_xor(v, m, 64);
    v = (o > v) ? o : v;
  }
  return v;
}

// Fused {block argmax -> tagged slot store -> all-blocks poll -> local reduce}.
// Slot format: f32bits<<32 | (t+1)<<17 | idx   (idx < 2^17, tag fits 15 bits;
// memset-0 init never matches). Double-buffered by t&1: blocks are at most one
// phase apart, so a slot is never overwritten while still being polled.
__device__ __forceinline__ int roundSync(float val, unsigned pidx, int t,
                                         ull* __restrict__ partials, int nblk,
                                         ull* s_w, ull* s_r,
                                         int tid, int lane, int wid, int blockId) {
  ull key = wredmax(pkkey(val, pidx));
  if (lane == 0) s_w[wid] = key;
  __syncthreads();
  if (tid == 0) {
    ull m = s_w[0];
#pragma unroll
    for (int i = 1; i < NTHR / 64; ++i) { ull o = s_w[i]; if (o > m) m = o; }
    unsigned idx = ~(unsigned)m;  // low word was ~idx
    ull slotv = (m & 0xFFFFFFFF00000000ull) | ((ull)(unsigned)(t + 1) << 17) | (ull)idx;
    __hip_atomic_store(&partials[(t & 1) * nblk + blockId], slotv,
                       __ATOMIC_RELEASE, __HIP_MEMORY_SCOPE_AGENT);
  }
  // poll all slots in parallel (one per thread), short-sleep backoff
  ull ck = 0;
  if (tid < nblk) {
    ull* slot = &partials[(t & 1) * nblk + tid];
    const unsigned tag = (unsigned)(t + 1);
    ull v = __hip_atomic_load(slot, __ATOMIC_ACQUIRE, __HIP_MEMORY_SCOPE_AGENT);
    while (((unsigned)(v >> 17) & 0x7FFFu) != tag) {
      __builtin_amdgcn_s_sleep(2);
      v = __hip_atomic_load(slot, __ATOMIC_ACQUIRE, __HIP_MEMORY_SCOPE_AGENT);
    }
    unsigned idx = (unsigned)v & 0x1FFFFu;
    ck = (v & 0xFFFFFFFF00000000ull) | (ull)(~idx);
  }
  ck = wredmax(ck);
  if (lane == 0) s_r[wid] = ck;
  __syncthreads();
  ull m = s_r[0];
#pragma unroll
  for (int i = 1; i < NTHR / 64; ++i) { ull o = s_r[i]; if (o > m) m = o; }
  return (int)(~(unsigned)m);
}

// stage normalized selected row into LDS (f32 squares, exact f64 sum, f32 sqrt, IEEE f32 div)
__device__ __forceinline__ void stage(const float* __restrict__ feat, int c,
                                      float* s_sel, float* s_nrm, int tid, int lane) {
  const float* __restrict__ row = feat + (size_t)c * DD;
  if (tid < 64) {
    float x1 = row[lane], x2 = row[lane + 64];
    double s = (double)(x1 * x1) + (double)(x2 * x2);
#pragma unroll
    for (int m = 32; m; m >>= 1) s += __shfl_xor(s, m, 64);
    if (lane == 0) *s_nrm = fmaxf(sqrtf((float)s), 1e-12f);
  }
  __syncthreads();
  const float nm = *s_nrm;
  if (tid < DD) s_sel[tid] = row[tid] / nm;
  __syncthreads();
}

// distance of my half-point (64 floats in VGPRs) to the staged row
__device__ __forceinline__ float distTo(const float* p, const float* s_sel, int half) {
  const float* sp = s_sel + half * HD;
  double a0 = 0.0, a1 = 0.0, a2 = 0.0, a3 = 0.0;
#pragma unroll
  for (int j = 0; j < HD; j += 4) {
    float d0 = p[j]     - sp[j];
    float d1 = p[j + 1] - sp[j + 1];
    float d2 = p[j + 2] - sp[j + 2];
    float d3 = p[j + 3] - sp[j + 3];
    a0 += (double)(d0 * d0); a1 += (double)(d1 * d1);
    a2 += (double)(d2 * d2); a3 += (double)(d3 * d3);
  }
  double s = (a0 + a1) + (a2 + a3);
  s += __shfl_xor(s, 1, 64);   // combine the pair's halves (exact to ~2^-52)
  return sqrtf((float)s);
}

// waves_per_eu(4,4): 16-wave blocks at 1 block/CU = exactly 4 waves/EU, so max=4
// costs nothing -- but it lifts the allocator's occupancy target, giving a
// 512-VGPR/wave budget so the 64 pinned floats stay register-resident (no
// spill, no remat). Round-3 evidence: without it the allocator spills to hit
// the 64-VGPR occupancy bucket.
__global__ __launch_bounds__(NTHR)
__attribute__((amdgpu_waves_per_eu(4, 4)))
void fps_kernel(const float* __restrict__ feat, const float* __restrict__ att,
                const int* __restrict__ kptr, int* __restrict__ out,
                ull* __restrict__ partials, int N, int nblk) {
  __shared__ ull s_w[NTHR / 64];
  __shared__ ull s_r[NTHR / 64];
  __shared__ alignas(16) float s_sel[DD];
  __shared__ float s_nrm;

  const int tid  = threadIdx.x;
  const int lane = tid & 63;
  const int wid  = tid >> 6;
  const int gid  = blockIdx.x * NTHR + tid;
  const int pidx = gid >> 1;   // point index (2 threads per point)
  const int half = tid & 1;    // which 64-dim half this thread owns
  const int k    = kptr[0];

  if (k >= N) {  // reference returns arange(N)
    for (int i = gid; i < N && i < nblk * NTHR; i += nblk * NTHR) out[i] = i;
    return;
  }

  // ---- load my 64-dim half (coalesced float4) into a scalar array
  const float* __restrict__ base = feat + (size_t)gid * HD;
  float p[HD];
#pragma unroll
  for (int j = 0; j < HD; j += 4) {
    const float4 v = *reinterpret_cast<const float4*>(base + j);
    p[j] = v.x; p[j + 1] = v.y; p[j + 2] = v.z; p[j + 3] = v.w;
  }

  // ---- L2-normalize (f32 squares, exact f64 sum across both halves)
  {
    double a0 = 0.0, a1 = 0.0, a2 = 0.0, a3 = 0.0;
#pragma unroll
    for (int j = 0; j < HD; j += 4) {
      a0 += (double)(p[j] * p[j]);         a1 += (double)(p[j + 1] * p[j + 1]);
      a2 += (double)(p[j + 2] * p[j + 2]); a3 += (double)(p[j + 3] * p[j + 3]);
    }
    double s = (a0 + a1) + (a2 + a3);
    s += __shfl_xor(s, 1, 64);
    float nm = fmaxf(sqrtf((float)s), 1e-12f);
#pragma unroll
    for (int j = 0; j < HD; ++j) {
      p[j] = p[j] / nm;
      asm volatile("" : "+v"(p[j]));  // pin: no remat-from-global, stays in VGPR
    }
  }

  // ---- phase A: argmax(attention_scores)
  int far = roundSync(att[pidx], (unsigned)pidx, 0, partials, nblk,
                      s_w, s_r, tid, lane, wid, blockIdx.x);
  if (gid == 0) out[0] = far;

  stage(feat, far, s_sel, &s_nrm, tid, lane);
  float mind = distTo(p, s_sel, half);
  if (pidx == far) mind = -__builtin_inff();

  // ---- main FPS loop
  for (int t = 1; t < k; ++t) {
    far = roundSync(mind, (unsigned)pidx, t, partials, nblk,
                    s_w, s_r, tid, lane, wid, blockIdx.x);
    if (gid == 0) out[t] = far;

    stage(feat, far, s_sel, &s_nrm, tid, lane);
    float d = distTo(p, s_sel, half);
    mind = fminf(mind, d);
    if (pidx == far) mind = -__builtin_inff();
  }
}

extern "C" void kernel_launch(void* const* d_in, const int* in_sizes, int n_in,
                              void* d_out, int out_size, void* d_ws, size_t ws_size,
                              hipStream_t stream) {
  const float* feat = (const float*)d_in[0];
  const float* att  = (const float*)d_in[1];
  const int*   kptr = (const int*)d_in[2];
  int* out = (int*)d_out;

  const int N    = in_sizes[1];        // 131072
  const int nblk = (2 * N) / NTHR;     // 256 blocks -> 1 per CU, all co-resident

  ull* partials = (ull*)d_ws;
  // zero the tagged slots every call (graph-replay determinism; tag>=1 never matches 0)
  hipMemsetAsync(d_ws, 0, (size_t)(2 * nblk * sizeof(ull)), stream);
  fps_kernel<<<nblk, NTHR, 0, stream>>>(feat, att, kptr, out, partials, N, nblk);
}